// Round 16
// baseline (488.071 us; speedup 1.0000x reference)
//
#include <hip/hip_runtime.h>
#include <math.h>

#define NXR 8192
#define NCR 8192
#define HD  512
#define NSL 8            // attention j-slices (R11-proven)
#define JC  (NCR / NSL)  // 1024 cols per attention block
#define KSTR 520         // padded LDS col stride (elems)

typedef short s16x8 __attribute__((ext_vector_type(8)));
typedef float f32x4 __attribute__((ext_vector_type(4)));
typedef unsigned short u16;

struct P11 { const float* p[11]; };
struct P3  { const float* p[3]; };
struct MB11 { const float* p[11]; };  // 0..8: bh[l*3+net]; 9: Qbo; 10: Kbo

__device__ inline u16 f2bf(float f) {
    unsigned int u = __float_as_uint(f);
    u = (u + 0x7FFFu + ((u >> 16) & 1u)) >> 16;
    return (u16)u;
}
__device__ inline float bf2f(u16 h) {
    return __uint_as_float(((unsigned int)h) << 16);
}

// ---------------------------------------------------------------------------
// Fused weight transpose + bf16 convert: out[z][n][k] = (bf16)in_z[k][n].
// Slots: z = l*3+net (hidden), 9 = QWo, 10 = KWo. grid (16,16,11).
// ---------------------------------------------------------------------------
__global__ __launch_bounds__(256) void transpose_w_all(
    P11 srcs, u16* __restrict__ out)
{
    const float* in = srcs.p[blockIdx.z];
    u16* o = out + (size_t)blockIdx.z * HD * HD;
    __shared__ float tile[32][33];
    int bx = blockIdx.x * 32, by = blockIdx.y * 32;
    int tx = threadIdx.x & 31, ty = threadIdx.x >> 5;
    for (int r = ty; r < 32; r += 8)
        tile[r][tx] = in[(size_t)(by + r) * HD + bx + tx];
    __syncthreads();
    for (int r = ty; r < 32; r += 8)
        o[(size_t)(bx + r) * HD + by + tx] = f2bf(tile[tx][r]);
}

// ---------------------------------------------------------------------------
// Layer 0, 8 outputs/thread, bf16x8 store. grid (NXR*HD/2048, 1, 3)
// ---------------------------------------------------------------------------
__global__ __launch_bounds__(256) void layer0_all(
    const float* __restrict__ x, const float* __restrict__ c,
    P3 W0p, P3 b0p, u16* __restrict__ H)
{
    int z = blockIdx.z;
    const float* X  = (z == 0) ? x : c;
    const float* W0 = W0p.p[z];
    const float* b0 = b0p.p[z];
    u16* Hn = H + (size_t)z * NXR * HD;

    int idx = (blockIdx.x * 256 + threadIdx.x) * 8;
    int n = idx & (HD - 1);
    int row = idx >> 9;
    float x0 = X[row * 3 + 0], x1 = X[row * 3 + 1], x2 = X[row * 3 + 2];
    s16x8 o;
#pragma unroll
    for (int j = 0; j < 8; ++j) {
        float v = x0 * W0[n + j] + x1 * W0[HD + n + j] + x2 * W0[2 * HD + n + j] + b0[n + j];
        ((u16*)&o)[j] = f2bf(__sinf(v));
    }
    *(s16x8*)&Hn[idx] = o;
}

// ---------------------------------------------------------------------------
// MLP MEGA-KERNEL v2: hidden+output layers in ONE dispatch, row-band
// parallel, IN-PLACE per 128-row strip (validated R15: all qf reads of a
// layer complete before its first store; __threadfence between layers).
// v2 vs R15: NO V-epilogue in-kernel (that blew VGPR to 256 and spilled
// 70 MB scratch) — vout is a separate proven dispatch. Outer loops
// unroll-disabled to keep register pressure at the gemm_rs level.
// Q/K nets: 4 layers (3 sin + linear out). V net: 3 sin layers.
// grid (64, 1, 3) = 192 blocks.
// ---------------------------------------------------------------------------
__global__ __launch_bounds__(256) void mlp_mega(
    u16* __restrict__ h, const u16* __restrict__ wT,
    MB11 mb)
{
    __shared__ u16 Ws[32 * KSTR];      // 33,280 B

    const size_t WTN = (size_t)HD * HD;
    const int net = blockIdx.z;
    const int tid = threadIdx.x;
    const int wave = tid >> 6, lane = tid & 63;
    const int row0 = blockIdx.x * 128;
    u16* strip = h + (size_t)net * NXR * HD;

    const int qm = lane & 15;
    const int g  = lane >> 4;

    const int nlayers = (net == 2) ? 3 : 4;

#pragma unroll 1
    for (int layer = 0; layer < nlayers; ++layer) {
        const u16* Wt = (layer < 3) ? wT + (size_t)(layer * 3 + net) * WTN
                                    : wT + (size_t)(9 + net) * WTN;
        const float* bias_p = mb.p[(layer < 3) ? layer * 3 + net : 9 + net];
        const int act = (layer < 3);

        // ---- load this wave's 32 rows, all K, into registers (AGPR-parked) --
        s16x8 qf[16][2];
        {
            const u16* ap = strip + (size_t)(row0 + wave * 32 + qm) * HD + g * 8;
#pragma unroll
            for (int t = 0; t < 16; ++t) {
                qf[t][0] = *(const s16x8*)(ap + t * 32);
                qf[t][1] = *(const s16x8*)(ap + (size_t)16 * HD + t * 32);
            }
        }

#pragma unroll 1
        for (int ct = 0; ct < 16; ++ct) {
            const int col0 = ct * 32;

            // stage W tile [32 cols][512] into LDS
#pragma unroll
            for (int i = 0; i < 8; ++i) {
                int chunk = i * 256 + tid;
                int cc = chunk >> 6, ch = chunk & 63;
                s16x8 v = *(const s16x8*)(Wt + (size_t)(col0 + cc) * HD + ch * 8);
                *(s16x8*)&Ws[cc * KSTR + ch * 8] = v;
            }
            __syncthreads();

            f32x4 acc[2][2] = {};
#pragma unroll
            for (int kt = 0; kt < 16; ++kt) {
                s16x8 b0 = *(const s16x8*)&Ws[qm * KSTR + kt * 32 + g * 8];
                s16x8 b1 = *(const s16x8*)&Ws[(16 + qm) * KSTR + kt * 32 + g * 8];
                acc[0][0] = __builtin_amdgcn_mfma_f32_16x16x32_bf16(qf[kt][0], b0, acc[0][0], 0, 0, 0);
                acc[0][1] = __builtin_amdgcn_mfma_f32_16x16x32_bf16(qf[kt][0], b1, acc[0][1], 0, 0, 0);
                acc[1][0] = __builtin_amdgcn_mfma_f32_16x16x32_bf16(qf[kt][1], b0, acc[1][0], 0, 0, 0);
                acc[1][1] = __builtin_amdgcn_mfma_f32_16x16x32_bf16(qf[kt][1], b1, acc[1][1], 0, 0, 0);
            }

            float bv0 = bias_p[col0 + qm];
            float bv1 = bias_p[col0 + 16 + qm];
#pragma unroll
            for (int hh = 0; hh < 2; ++hh) {
#pragma unroll
                for (int r = 0; r < 4; ++r) {
                    int grow = row0 + wave * 32 + hh * 16 + g * 4 + r;
                    float v0 = acc[hh][0][r] + bv0;
                    float v1 = acc[hh][1][r] + bv1;
                    if (act) { v0 = __sinf(v0); v1 = __sinf(v1); }
                    strip[(size_t)grow * HD + col0 + qm]      = f2bf(v0);
                    strip[(size_t)grow * HD + col0 + 16 + qm] = f2bf(v1);
                }
            }
            __syncthreads();   // Ws reused next col-tile
        }
        __threadfence();       // stores visible before next layer's qf reload
    }
}

// ---------------------------------------------------------------------------
// V output layer (M=3), one wave per row, fp32 out.
// ---------------------------------------------------------------------------
__global__ __launch_bounds__(256) void vout_k(
    const u16* __restrict__ H, const float* __restrict__ Wo,
    const float* __restrict__ bo, float* __restrict__ V)
{
    int wave = threadIdx.x >> 6, lane = threadIdx.x & 63;
    int row = blockIdx.x * 4 + wave;
    s16x8 hv = *(const s16x8*)(H + (size_t)row * HD + lane * 8);
    float a0 = 0, a1 = 0, a2 = 0;
#pragma unroll
    for (int j = 0; j < 8; ++j) {
        float hf = bf2f(((const u16*)&hv)[j]);
        int k = lane * 8 + j;
        a0 += hf * Wo[k * 3 + 0];
        a1 += hf * Wo[k * 3 + 1];
        a2 += hf * Wo[k * 3 + 2];
    }
#pragma unroll
    for (int d = 32; d >= 1; d >>= 1) {
        a0 += __shfl_down(a0, d);
        a1 += __shfl_down(a1, d);
        a2 += __shfl_down(a2, d);
    }
    if (lane == 0) {
        V[row * 3 + 0] = a0 + bo[0];
        V[row * 3 + 1] = a1 + bo[1];
        V[row * 3 + 2] = a2 + bo[2];
    }
}

// ---------------------------------------------------------------------------
// Fused attention (R11-exact): Q-in-registers (32 rows/wave), K-in-LDS.
// Block = 128 Q-rows x JC=1024 cols; grid (NSL=8, 64) = 512 blocks.
// ---------------------------------------------------------------------------
__global__ __launch_bounds__(256) void attn_mfma(
    const u16* __restrict__ Q, const u16* __restrict__ K,
    const float* __restrict__ V, float* __restrict__ out)
{
    __shared__ u16 Ks[32 * KSTR];   // 33,280 B

    const int tid = threadIdx.x;
    const int wave = tid >> 6, lane = tid & 63;
    const int row0 = blockIdx.y * 128;
    const int col_base = blockIdx.x * JC;

    const int qm = lane & 15;
    const int g  = lane >> 4;

    s16x8 qf[16][2];
    {
        const u16* qp = Q + (size_t)(row0 + wave * 32 + qm) * HD + g * 8;
#pragma unroll
        for (int t = 0; t < 16; ++t) {
            qf[t][0] = *(const s16x8*)(qp + t * 32);
            qf[t][1] = *(const s16x8*)(qp + (size_t)16 * HD + t * 32);
        }
    }

    float po[2][4][3] = {};

    for (int jt = 0; jt < JC / 32; ++jt) {
        const int col0 = col_base + jt * 32;

#pragma unroll
        for (int i = 0; i < 8; ++i) {
            int chunk = i * 256 + tid;
            int cc = chunk >> 6;
            int ch = chunk & 63;
            s16x8 v = *(const s16x8*)(K + (size_t)(col0 + cc) * HD + ch * 8);
            *(s16x8*)&Ks[cc * KSTR + ch * 8] = v;
        }
        __syncthreads();

        float vv[2][3];
#pragma unroll
        for (int ct = 0; ct < 2; ++ct) {
            size_t vr = (size_t)(col0 + ct * 16 + qm) * 3;
            vv[ct][0] = V[vr + 0];
            vv[ct][1] = V[vr + 1];
            vv[ct][2] = V[vr + 2];
        }

        f32x4 acc[2][2] = {};
#pragma unroll
        for (int kt = 0; kt < 16; ++kt) {
            s16x8 b0 = *(const s16x8*)&Ks[qm * KSTR + kt * 32 + g * 8];
            s16x8 b1 = *(const s16x8*)&Ks[(16 + qm) * KSTR + kt * 32 + g * 8];
            acc[0][0] = __builtin_amdgcn_mfma_f32_16x16x32_bf16(qf[kt][0], b0, acc[0][0], 0, 0, 0);
            acc[0][1] = __builtin_amdgcn_mfma_f32_16x16x32_bf16(qf[kt][0], b1, acc[0][1], 0, 0, 0);
            acc[1][0] = __builtin_amdgcn_mfma_f32_16x16x32_bf16(qf[kt][1], b0, acc[1][0], 0, 0, 0);
            acc[1][1] = __builtin_amdgcn_mfma_f32_16x16x32_bf16(qf[kt][1], b1, acc[1][1], 0, 0, 0);
        }

        // sigmoid + PV (rcp = v_rcp_f32, 1 ulp)
#pragma unroll
        for (int h = 0; h < 2; ++h)
#pragma unroll
            for (int ct = 0; ct < 2; ++ct)
#pragma unroll
                for (int r = 0; r < 4; ++r) {
                    float s = __builtin_amdgcn_rcpf(1.f + __expf(-acc[h][ct][r]));
                    po[h][r][0] += s * vv[ct][0];
                    po[h][r][1] += s * vv[ct][1];
                    po[h][r][2] += s * vv[ct][2];
                }
        __syncthreads();
    }

#pragma unroll
    for (int h = 0; h < 2; ++h)
#pragma unroll
        for (int r = 0; r < 4; ++r)
#pragma unroll
            for (int c = 0; c < 3; ++c) {
                float v = po[h][r][c];
                v += __shfl_down(v, 8, 16);
                v += __shfl_down(v, 4, 16);
                v += __shfl_down(v, 2, 16);
                v += __shfl_down(v, 1, 16);
                if (qm == 0)
                    atomicAdd(&out[(size_t)(row0 + wave * 32 + h * 16 + g * 4 + r) * 3 + c], v);
            }
}

// ---------------------------------------------------------------------------
// Workspace (single path, 29.6 MB — under the R5-proven 38.1 MB):
//   wT [0, 5.50 MB) | h [5.50, 29.50 MB) (3 net strips, in-place MLP)
//   | Vf [29.50, 29.60 MB)
// ---------------------------------------------------------------------------
extern "C" void kernel_launch(void* const* d_in, const int* in_sizes, int n_in,
                              void* d_out, int out_size, void* d_ws, size_t ws_size,
                              hipStream_t stream)
{
    const float* x   = (const float*)d_in[0];
    const float* c   = (const float*)d_in[1];
    const float* QW0 = (const float*)d_in[2];
    const float* Qb0 = (const float*)d_in[3];
    const float* QWh = (const float*)d_in[4];
    const float* Qbh = (const float*)d_in[5];
    const float* QWo = (const float*)d_in[6];
    const float* Qbo = (const float*)d_in[7];
    const float* KW0 = (const float*)d_in[8];
    const float* Kb0 = (const float*)d_in[9];
    const float* KWh = (const float*)d_in[10];
    const float* Kbh = (const float*)d_in[11];
    const float* KWo = (const float*)d_in[12];
    const float* Kbo = (const float*)d_in[13];
    const float* VW0 = (const float*)d_in[14];
    const float* Vb0 = (const float*)d_in[15];
    const float* VWh = (const float*)d_in[16];
    const float* Vbh = (const float*)d_in[17];
    const float* VWo = (const float*)d_in[18];
    const float* Vbo = (const float*)d_in[19];

    char* ws = (char*)d_ws;
    const size_t WTN = (size_t)HD * HD;
    const size_t NET = (size_t)NXR * HD;

    u16*   wT = (u16*)ws;                                   // 5.5 MB
    u16*   hA = (u16*)(ws + 11 * WTN * sizeof(u16));        // 24 MB (3 strips)
    float* Vf = (float*)(ws + 11 * WTN * sizeof(u16) + 3 * NET * sizeof(u16));

    // ---- weight transposes (1 dispatch) ----
    P11 tsrc;
    for (int l = 0; l < 3; ++l) {
        tsrc.p[l * 3 + 0] = QWh + (size_t)l * WTN;
        tsrc.p[l * 3 + 1] = KWh + (size_t)l * WTN;
        tsrc.p[l * 3 + 2] = VWh + (size_t)l * WTN;
    }
    tsrc.p[9]  = QWo;
    tsrc.p[10] = KWo;
    transpose_w_all<<<dim3(16, 16, 11), 256, 0, stream>>>(tsrc, wT);

    // ---- layer 0 (1 dispatch, 3 nets) ----
    {
        P3 w0 = {{QW0, KW0, VW0}}, b0 = {{Qb0, Kb0, Vb0}};
        layer0_all<<<dim3(NXR * HD / 2048, 1, 3), 256, 0, stream>>>(x, c, w0, b0, hA);
    }

    // ---- MLP mega-kernel v2 (1 dispatch: all hidden + Q/K output layers) ----
    {
        MB11 mb;
        for (int l = 0; l < 3; ++l) {
            mb.p[l * 3 + 0] = Qbh + (size_t)l * HD;
            mb.p[l * 3 + 1] = Kbh + (size_t)l * HD;
            mb.p[l * 3 + 2] = Vbh + (size_t)l * HD;
        }
        mb.p[9]  = Qbo;
        mb.p[10] = Kbo;
        mlp_mega<<<dim3(NXR / 128, 1, 3), 256, 0, stream>>>(hA, wT, mb);
    }

    // ---- V output layer ----
    vout_k<<<NCR / 4, 256, 0, stream>>>(hA + 2 * NET, VWo, Vbo, Vf);

    // ---- attention ----
    hipMemsetAsync(d_out, 0, (size_t)out_size * sizeof(float), stream);
    attn_mfma<<<dim3(NSL, NXR / 128), 256, 0, stream>>>(
        hA, hA + NET, Vf, (float*)d_out);
}

// Round 17
// 449.825 us; speedup vs baseline: 1.0850x; 1.0850x over previous
//
#include <hip/hip_runtime.h>
#include <math.h>

#define NXR 8192
#define NCR 8192
#define HD  512
#define NSL 8            // attention j-slices (R11-proven)
#define JC  (NCR / NSL)  // 1024 cols per attention block
#define KSTR 520         // padded LDS col stride (elems)

typedef short s16x8 __attribute__((ext_vector_type(8)));
typedef float f32x4 __attribute__((ext_vector_type(4)));
typedef unsigned short u16;

struct P11 { const float* p[11]; };
struct P3  { const float* p[3]; };
struct MB11 { const float* p[11]; };  // 0..8: bh[l*3+net]; 9: Qbo; 10: Kbo

__device__ inline u16 f2bf(float f) {
    unsigned int u = __float_as_uint(f);
    u = (u + 0x7FFFu + ((u >> 16) & 1u)) >> 16;
    return (u16)u;
}
__device__ inline float bf2f(u16 h) {
    return __uint_as_float(((unsigned int)h) << 16);
}

// ---------------------------------------------------------------------------
// Fused weight transpose + bf16 convert: out[z][n][k] = (bf16)in_z[k][n].
// Slots: z = l*3+net (hidden), 9 = QWo, 10 = KWo. grid (16,16,11).
// ---------------------------------------------------------------------------
__global__ __launch_bounds__(256) void transpose_w_all(
    P11 srcs, u16* __restrict__ out)
{
    const float* in = srcs.p[blockIdx.z];
    u16* o = out + (size_t)blockIdx.z * HD * HD;
    __shared__ float tile[32][33];
    int bx = blockIdx.x * 32, by = blockIdx.y * 32;
    int tx = threadIdx.x & 31, ty = threadIdx.x >> 5;
    for (int r = ty; r < 32; r += 8)
        tile[r][tx] = in[(size_t)(by + r) * HD + bx + tx];
    __syncthreads();
    for (int r = ty; r < 32; r += 8)
        o[(size_t)(bx + r) * HD + by + tx] = f2bf(tile[tx][r]);
}

// ---------------------------------------------------------------------------
// Layer 0, 8 outputs/thread, bf16x8 store. grid (NXR*HD/2048, 1, 3)
// ---------------------------------------------------------------------------
__global__ __launch_bounds__(256) void layer0_all(
    const float* __restrict__ x, const float* __restrict__ c,
    P3 W0p, P3 b0p, u16* __restrict__ H)
{
    int z = blockIdx.z;
    const float* X  = (z == 0) ? x : c;
    const float* W0 = W0p.p[z];
    const float* b0 = b0p.p[z];
    u16* Hn = H + (size_t)z * NXR * HD;

    int idx = (blockIdx.x * 256 + threadIdx.x) * 8;
    int n = idx & (HD - 1);
    int row = idx >> 9;
    float x0 = X[row * 3 + 0], x1 = X[row * 3 + 1], x2 = X[row * 3 + 2];
    s16x8 o;
#pragma unroll
    for (int j = 0; j < 8; ++j) {
        float v = x0 * W0[n + j] + x1 * W0[HD + n + j] + x2 * W0[2 * HD + n + j] + b0[n + j];
        ((u16*)&o)[j] = f2bf(__sinf(v));
    }
    *(s16x8*)&Hn[idx] = o;
}

// ---------------------------------------------------------------------------
// MLP MEGA-KERNEL v3: all layers, one dispatch, 64-ROW strips for
// co-residency (v2's 128-row/192-block grid = 0.75 blocks/CU exposed every
// latency; measured 298 us at 8% occupancy).
// grid (128, 1, 3) = 384 blocks (1.5/CU); wave holds 16 rows (qf[16][1] =
// 64 regs -> ~130 total -> 3 waves/SIMD headroom, all blocks co-resident).
// Per layer: load qf -> 16 col-tiles (stage W 32x512 in LDS; kt-loop
// 2 ds_read_b128 + 2 MFMA). In-place strip update (validated R15/R16),
// __threadfence between layers. Q/K: 4 layers; V: 3.
// ---------------------------------------------------------------------------
__global__ __launch_bounds__(256) void mlp_mega(
    u16* __restrict__ h, const u16* __restrict__ wT,
    MB11 mb)
{
    __shared__ u16 Ws[32 * KSTR];      // 33,280 B

    const size_t WTN = (size_t)HD * HD;
    const int net = blockIdx.z;
    const int tid = threadIdx.x;
    const int wave = tid >> 6, lane = tid & 63;
    const int row0 = blockIdx.x * 64;
    u16* strip = h + (size_t)net * NXR * HD;

    const int qm = lane & 15;
    const int g  = lane >> 4;

    const int nlayers = (net == 2) ? 3 : 4;

#pragma unroll 1
    for (int layer = 0; layer < nlayers; ++layer) {
        const u16* Wt = (layer < 3) ? wT + (size_t)(layer * 3 + net) * WTN
                                    : wT + (size_t)(9 + net) * WTN;
        const float* bias_p = mb.p[(layer < 3) ? layer * 3 + net : 9 + net];
        const int act = (layer < 3);

        // ---- load this wave's 16 rows, all K, into registers ----
        s16x8 qf[16];
        {
            const u16* ap = strip + (size_t)(row0 + wave * 16 + qm) * HD + g * 8;
#pragma unroll
            for (int t = 0; t < 16; ++t)
                qf[t] = *(const s16x8*)(ap + t * 32);
        }

#pragma unroll 1
        for (int ct = 0; ct < 16; ++ct) {
            const int col0 = ct * 32;

            // stage W tile [32 cols][512] into LDS
#pragma unroll
            for (int i = 0; i < 8; ++i) {
                int chunk = i * 256 + tid;
                int cc = chunk >> 6, ch = chunk & 63;
                s16x8 v = *(const s16x8*)(Wt + (size_t)(col0 + cc) * HD + ch * 8);
                *(s16x8*)&Ws[cc * KSTR + ch * 8] = v;
            }
            __syncthreads();

            f32x4 acc[2] = {};
#pragma unroll
            for (int kt = 0; kt < 16; ++kt) {
                s16x8 b0 = *(const s16x8*)&Ws[qm * KSTR + kt * 32 + g * 8];
                s16x8 b1 = *(const s16x8*)&Ws[(16 + qm) * KSTR + kt * 32 + g * 8];
                acc[0] = __builtin_amdgcn_mfma_f32_16x16x32_bf16(qf[kt], b0, acc[0], 0, 0, 0);
                acc[1] = __builtin_amdgcn_mfma_f32_16x16x32_bf16(qf[kt], b1, acc[1], 0, 0, 0);
            }

            float bv0 = bias_p[col0 + qm];
            float bv1 = bias_p[col0 + 16 + qm];
#pragma unroll
            for (int r = 0; r < 4; ++r) {
                int grow = row0 + wave * 16 + g * 4 + r;
                float v0 = acc[0][r] + bv0;
                float v1 = acc[1][r] + bv1;
                if (act) { v0 = __sinf(v0); v1 = __sinf(v1); }
                strip[(size_t)grow * HD + col0 + qm]      = f2bf(v0);
                strip[(size_t)grow * HD + col0 + 16 + qm] = f2bf(v1);
            }
            __syncthreads();   // Ws reused next col-tile
        }
        __threadfence();       // stores visible before next layer's qf reload
    }
}

// ---------------------------------------------------------------------------
// V output layer (M=3), one wave per row, fp32 out.
// ---------------------------------------------------------------------------
__global__ __launch_bounds__(256) void vout_k(
    const u16* __restrict__ H, const float* __restrict__ Wo,
    const float* __restrict__ bo, float* __restrict__ V)
{
    int wave = threadIdx.x >> 6, lane = threadIdx.x & 63;
    int row = blockIdx.x * 4 + wave;
    s16x8 hv = *(const s16x8*)(H + (size_t)row * HD + lane * 8);
    float a0 = 0, a1 = 0, a2 = 0;
#pragma unroll
    for (int j = 0; j < 8; ++j) {
        float hf = bf2f(((const u16*)&hv)[j]);
        int k = lane * 8 + j;
        a0 += hf * Wo[k * 3 + 0];
        a1 += hf * Wo[k * 3 + 1];
        a2 += hf * Wo[k * 3 + 2];
    }
#pragma unroll
    for (int d = 32; d >= 1; d >>= 1) {
        a0 += __shfl_down(a0, d);
        a1 += __shfl_down(a1, d);
        a2 += __shfl_down(a2, d);
    }
    if (lane == 0) {
        V[row * 3 + 0] = a0 + bo[0];
        V[row * 3 + 1] = a1 + bo[1];
        V[row * 3 + 2] = a2 + bo[2];
    }
}

// ---------------------------------------------------------------------------
// Fused attention (R14-exact): Q-in-registers (32 rows/wave), K-in-LDS.
// Block = 128 Q-rows x JC=1024 cols; grid (NSL=8, 64) = 512 blocks.
// ---------------------------------------------------------------------------
__global__ __launch_bounds__(256) void attn_mfma(
    const u16* __restrict__ Q, const u16* __restrict__ K,
    const float* __restrict__ V, float* __restrict__ out)
{
    __shared__ u16 Ks[32 * KSTR];   // 33,280 B

    const int tid = threadIdx.x;
    const int wave = tid >> 6, lane = tid & 63;
    const int row0 = blockIdx.y * 128;
    const int col_base = blockIdx.x * JC;

    const int qm = lane & 15;
    const int g  = lane >> 4;

    s16x8 qf[16][2];
    {
        const u16* qp = Q + (size_t)(row0 + wave * 32 + qm) * HD + g * 8;
#pragma unroll
        for (int t = 0; t < 16; ++t) {
            qf[t][0] = *(const s16x8*)(qp + t * 32);
            qf[t][1] = *(const s16x8*)(qp + (size_t)16 * HD + t * 32);
        }
    }

    float po[2][4][3] = {};

    for (int jt = 0; jt < JC / 32; ++jt) {
        const int col0 = col_base + jt * 32;

#pragma unroll
        for (int i = 0; i < 8; ++i) {
            int chunk = i * 256 + tid;
            int cc = chunk >> 6;
            int ch = chunk & 63;
            s16x8 v = *(const s16x8*)(K + (size_t)(col0 + cc) * HD + ch * 8);
            *(s16x8*)&Ks[cc * KSTR + ch * 8] = v;
        }
        __syncthreads();

        float vv[2][3];
#pragma unroll
        for (int ct = 0; ct < 2; ++ct) {
            size_t vr = (size_t)(col0 + ct * 16 + qm) * 3;
            vv[ct][0] = V[vr + 0];
            vv[ct][1] = V[vr + 1];
            vv[ct][2] = V[vr + 2];
        }

        f32x4 acc[2][2] = {};
#pragma unroll
        for (int kt = 0; kt < 16; ++kt) {
            s16x8 b0 = *(const s16x8*)&Ks[qm * KSTR + kt * 32 + g * 8];
            s16x8 b1 = *(const s16x8*)&Ks[(16 + qm) * KSTR + kt * 32 + g * 8];
            acc[0][0] = __builtin_amdgcn_mfma_f32_16x16x32_bf16(qf[kt][0], b0, acc[0][0], 0, 0, 0);
            acc[0][1] = __builtin_amdgcn_mfma_f32_16x16x32_bf16(qf[kt][0], b1, acc[0][1], 0, 0, 0);
            acc[1][0] = __builtin_amdgcn_mfma_f32_16x16x32_bf16(qf[kt][1], b0, acc[1][0], 0, 0, 0);
            acc[1][1] = __builtin_amdgcn_mfma_f32_16x16x32_bf16(qf[kt][1], b1, acc[1][1], 0, 0, 0);
        }

        // sigmoid + PV (rcp = v_rcp_f32, 1 ulp)
#pragma unroll
        for (int h = 0; h < 2; ++h)
#pragma unroll
            for (int ct = 0; ct < 2; ++ct)
#pragma unroll
                for (int r = 0; r < 4; ++r) {
                    float s = __builtin_amdgcn_rcpf(1.f + __expf(-acc[h][ct][r]));
                    po[h][r][0] += s * vv[ct][0];
                    po[h][r][1] += s * vv[ct][1];
                    po[h][r][2] += s * vv[ct][2];
                }
        __syncthreads();
    }

#pragma unroll
    for (int h = 0; h < 2; ++h)
#pragma unroll
        for (int r = 0; r < 4; ++r)
#pragma unroll
            for (int c = 0; c < 3; ++c) {
                float v = po[h][r][c];
                v += __shfl_down(v, 8, 16);
                v += __shfl_down(v, 4, 16);
                v += __shfl_down(v, 2, 16);
                v += __shfl_down(v, 1, 16);
                if (qm == 0)
                    atomicAdd(&out[(size_t)(row0 + wave * 32 + h * 16 + g * 4 + r) * 3 + c], v);
            }
}

// ---------------------------------------------------------------------------
// Workspace (single path, 29.6 MB):
//   wT [0, 5.50 MB) | h [5.50, 29.50 MB) (3 net strips, in-place MLP)
//   | Vf [29.50, 29.60 MB)
// ---------------------------------------------------------------------------
extern "C" void kernel_launch(void* const* d_in, const int* in_sizes, int n_in,
                              void* d_out, int out_size, void* d_ws, size_t ws_size,
                              hipStream_t stream)
{
    const float* x   = (const float*)d_in[0];
    const float* c   = (const float*)d_in[1];
    const float* QW0 = (const float*)d_in[2];
    const float* Qb0 = (const float*)d_in[3];
    const float* QWh = (const float*)d_in[4];
    const float* Qbh = (const float*)d_in[5];
    const float* QWo = (const float*)d_in[6];
    const float* Qbo = (const float*)d_in[7];
    const float* KW0 = (const float*)d_in[8];
    const float* Kb0 = (const float*)d_in[9];
    const float* KWh = (const float*)d_in[10];
    const float* Kbh = (const float*)d_in[11];
    const float* KWo = (const float*)d_in[12];
    const float* Kbo = (const float*)d_in[13];
    const float* VW0 = (const float*)d_in[14];
    const float* Vb0 = (const float*)d_in[15];
    const float* VWh = (const float*)d_in[16];
    const float* Vbh = (const float*)d_in[17];
    const float* VWo = (const float*)d_in[18];
    const float* Vbo = (const float*)d_in[19];

    char* ws = (char*)d_ws;
    const size_t WTN = (size_t)HD * HD;
    const size_t NET = (size_t)NXR * HD;

    u16*   wT = (u16*)ws;                                   // 5.5 MB
    u16*   hA = (u16*)(ws + 11 * WTN * sizeof(u16));        // 24 MB (3 strips)
    float* Vf = (float*)(ws + 11 * WTN * sizeof(u16) + 3 * NET * sizeof(u16));

    // ---- weight transposes (1 dispatch) ----
    P11 tsrc;
    for (int l = 0; l < 3; ++l) {
        tsrc.p[l * 3 + 0] = QWh + (size_t)l * WTN;
        tsrc.p[l * 3 + 1] = KWh + (size_t)l * WTN;
        tsrc.p[l * 3 + 2] = VWh + (size_t)l * WTN;
    }
    tsrc.p[9]  = QWo;
    tsrc.p[10] = KWo;
    transpose_w_all<<<dim3(16, 16, 11), 256, 0, stream>>>(tsrc, wT);

    // ---- layer 0 (1 dispatch, 3 nets) ----
    {
        P3 w0 = {{QW0, KW0, VW0}}, b0 = {{Qb0, Kb0, Vb0}};
        layer0_all<<<dim3(NXR * HD / 2048, 1, 3), 256, 0, stream>>>(x, c, w0, b0, hA);
    }

    // ---- MLP mega-kernel v3 (1 dispatch: all hidden + Q/K output layers) ----
    {
        MB11 mb;
        for (int l = 0; l < 3; ++l) {
            mb.p[l * 3 + 0] = Qbh + (size_t)l * HD;
            mb.p[l * 3 + 1] = Kbh + (size_t)l * HD;
            mb.p[l * 3 + 2] = Vbh + (size_t)l * HD;
        }
        mb.p[9]  = Qbo;
        mb.p[10] = Kbo;
        mlp_mega<<<dim3(NXR / 64, 1, 3), 256, 0, stream>>>(hA, wT, mb);
    }

    // ---- V output layer ----
    vout_k<<<NCR / 4, 256, 0, stream>>>(hA + 2 * NET, VWo, Vbo, Vf);

    // ---- attention ----
    hipMemsetAsync(d_out, 0, (size_t)out_size * sizeof(float), stream);
    attn_mfma<<<dim3(NSL, NXR / 128), 256, 0, stream>>>(
        hA, hA + NET, Vf, (float*)d_out);
}

// Round 18
// 291.041 us; speedup vs baseline: 1.6770x; 1.5456x over previous
//
#include <hip/hip_runtime.h>
#include <math.h>

#define NXR 8192
#define NCR 8192
#define HD  512
#define NSL 8            // attention j-slices (R11-proven)
#define JC  (NCR / NSL)  // 1024 cols per attention block
#define KSTR 520         // padded LDS col stride (elems)

typedef short s16x8 __attribute__((ext_vector_type(8)));
typedef float f32x4 __attribute__((ext_vector_type(4)));
typedef unsigned short u16;

struct P11 { const float* p[11]; };
struct P3  { const float* p[3]; };

__device__ inline u16 f2bf(float f) {
    unsigned int u = __float_as_uint(f);
    u = (u + 0x7FFFu + ((u >> 16) & 1u)) >> 16;
    return (u16)u;
}
__device__ inline float bf2f(u16 h) {
    return __uint_as_float(((unsigned int)h) << 16);
}

__device__ inline void async_load16(const void* g, void* l) {
    __builtin_amdgcn_global_load_lds(
        (const __attribute__((address_space(1))) unsigned int*)g,
        (__attribute__((address_space(3))) unsigned int*)l, 16, 0, 0);
}

// ---------------------------------------------------------------------------
// Fused weight transpose + bf16 convert: out[z][n][k] = (bf16)in_z[k][n].
// Slots: z = l*3+net (hidden), 9 = QWo, 10 = KWo. grid (16,16,11).
// ---------------------------------------------------------------------------
__global__ __launch_bounds__(256) void transpose_w_all(
    P11 srcs, u16* __restrict__ out)
{
    const float* in = srcs.p[blockIdx.z];
    u16* o = out + (size_t)blockIdx.z * HD * HD;
    __shared__ float tile[32][33];
    int bx = blockIdx.x * 32, by = blockIdx.y * 32;
    int tx = threadIdx.x & 31, ty = threadIdx.x >> 5;
    for (int r = ty; r < 32; r += 8)
        tile[r][tx] = in[(size_t)(by + r) * HD + bx + tx];
    __syncthreads();
    for (int r = ty; r < 32; r += 8)
        o[(size_t)(bx + r) * HD + by + tx] = f2bf(tile[tx][r]);
}

// ---------------------------------------------------------------------------
// Layer 0, 8 outputs/thread, bf16x8 store. grid (NXR*HD/2048, 1, 3)
// ---------------------------------------------------------------------------
__global__ __launch_bounds__(256) void layer0_all(
    const float* __restrict__ x, const float* __restrict__ c,
    P3 W0p, P3 b0p, u16* __restrict__ H)
{
    int z = blockIdx.z;
    const float* X  = (z == 0) ? x : c;
    const float* W0 = W0p.p[z];
    const float* b0 = b0p.p[z];
    u16* Hn = H + (size_t)z * NXR * HD;

    int idx = (blockIdx.x * 256 + threadIdx.x) * 8;
    int n = idx & (HD - 1);
    int row = idx >> 9;
    float x0 = X[row * 3 + 0], x1 = X[row * 3 + 1], x2 = X[row * 3 + 2];
    s16x8 o;
#pragma unroll
    for (int j = 0; j < 8; ++j) {
        float v = x0 * W0[n + j] + x1 * W0[HD + n + j] + x2 * W0[2 * HD + n + j] + b0[n + j];
        ((u16*)&o)[j] = f2bf(__sinf(v));
    }
    *(s16x8*)&Hn[idx] = o;
}

// ---------------------------------------------------------------------------
// GEMM v5 (A-in-registers; W staged via global_load_lds into DOUBLE-BUFFERED
// LDS, ONE barrier per tile): issue DMA for tile ct+1 into buf^1, compute
// tile ct from buf, barrier (drain is ~free: loads flew during compute).
// Removes all ds_writes + one barrier/tile vs R13.
// Block = 128 rows x 128 cols (4 col-tiles); grid (64, 4, nets).
// ---------------------------------------------------------------------------
template<int ACT>
__global__ __launch_bounds__(256) void gemm_rs(
    const u16* __restrict__ Abase, const u16* __restrict__ Wt0, size_t wstride,
    P3 bias, u16* __restrict__ Cbase)
{
    __shared__ u16 Ws[2][32 * KSTR];   // 2 x 33,280 B

    const int net = blockIdx.z;
    const u16* A  = Abase + (size_t)net * NXR * HD;
    const u16* Wt = Wt0 + (size_t)net * wstride;
    const float* bias_p = bias.p[net];
    u16* C = Cbase + (size_t)net * NXR * HD;

    const int tid = threadIdx.x;
    const int wave = tid >> 6, lane = tid & 63;
    const int row0 = blockIdx.x * 128;
    const int colbase = blockIdx.y * 128;

    const int qm = lane & 15;
    const int g  = lane >> 4;

    // prologue: DMA col-tile 0 into buf 0 (dest = uniform base + lane*16)
#pragma unroll
    for (int i = 0; i < 8; ++i) {
        int cc = i * 4 + wave;
        async_load16(Wt + (size_t)(colbase + cc) * HD + lane * 8,
                     &Ws[0][cc * KSTR + lane * 8]);
    }

    // A fragments for this wave's 32 rows, all K (AGPR-parked)
    s16x8 qf[16][2];
    {
        const u16* ap = A + (size_t)(row0 + wave * 32 + qm) * HD + g * 8;
#pragma unroll
        for (int t = 0; t < 16; ++t) {
            qf[t][0] = *(const s16x8*)(ap + t * 32);
            qf[t][1] = *(const s16x8*)(ap + (size_t)16 * HD + t * 32);
        }
    }
    __syncthreads();   // buf 0 ready

    int p = 0;
#pragma unroll 1
    for (int ct = 0; ct < 4; ++ct) {
        const int col0 = colbase + ct * 32;

        if (ct + 1 < 4) {
#pragma unroll
            for (int i = 0; i < 8; ++i) {
                int cc = i * 4 + wave;
                async_load16(Wt + (size_t)(colbase + (ct + 1) * 32 + cc) * HD + lane * 8,
                             &Ws[p ^ 1][cc * KSTR + lane * 8]);
            }
        }

        const u16* Wb = Ws[p];
        f32x4 acc[2][2] = {};
#pragma unroll
        for (int kt = 0; kt < 16; ++kt) {
            s16x8 b0 = *(const s16x8*)&Wb[qm * KSTR + kt * 32 + g * 8];
            s16x8 b1 = *(const s16x8*)&Wb[(16 + qm) * KSTR + kt * 32 + g * 8];
            acc[0][0] = __builtin_amdgcn_mfma_f32_16x16x32_bf16(qf[kt][0], b0, acc[0][0], 0, 0, 0);
            acc[0][1] = __builtin_amdgcn_mfma_f32_16x16x32_bf16(qf[kt][0], b1, acc[0][1], 0, 0, 0);
            acc[1][0] = __builtin_amdgcn_mfma_f32_16x16x32_bf16(qf[kt][1], b0, acc[1][0], 0, 0, 0);
            acc[1][1] = __builtin_amdgcn_mfma_f32_16x16x32_bf16(qf[kt][1], b1, acc[1][1], 0, 0, 0);
        }

        float bv0 = bias_p[col0 + qm];
        float bv1 = bias_p[col0 + 16 + qm];
#pragma unroll
        for (int hh = 0; hh < 2; ++hh) {
#pragma unroll
            for (int r = 0; r < 4; ++r) {
                int grow = row0 + wave * 32 + hh * 16 + g * 4 + r;
                float v0 = acc[hh][0][r] + bv0;
                float v1 = acc[hh][1][r] + bv1;
                if (ACT) { v0 = __sinf(v0); v1 = __sinf(v1); }
                C[(size_t)grow * HD + col0 + qm]      = f2bf(v0);
                C[(size_t)grow * HD + col0 + 16 + qm] = f2bf(v1);
            }
        }
        __syncthreads();   // all reads of buf p done; buf p^1 DMA drained
        p ^= 1;
    }
}

// ---------------------------------------------------------------------------
// V output layer (M=3), one wave per row, fp32 out.
// ---------------------------------------------------------------------------
__global__ __launch_bounds__(256) void vout_k(
    const u16* __restrict__ H, const float* __restrict__ Wo,
    const float* __restrict__ bo, float* __restrict__ V)
{
    int wave = threadIdx.x >> 6, lane = threadIdx.x & 63;
    int row = blockIdx.x * 4 + wave;
    s16x8 hv = *(const s16x8*)(H + (size_t)row * HD + lane * 8);
    float a0 = 0, a1 = 0, a2 = 0;
#pragma unroll
    for (int j = 0; j < 8; ++j) {
        float hf = bf2f(((const u16*)&hv)[j]);
        int k = lane * 8 + j;
        a0 += hf * Wo[k * 3 + 0];
        a1 += hf * Wo[k * 3 + 1];
        a2 += hf * Wo[k * 3 + 2];
    }
#pragma unroll
    for (int d = 32; d >= 1; d >>= 1) {
        a0 += __shfl_down(a0, d);
        a1 += __shfl_down(a1, d);
        a2 += __shfl_down(a2, d);
    }
    if (lane == 0) {
        V[row * 3 + 0] = a0 + bo[0];
        V[row * 3 + 1] = a1 + bo[1];
        V[row * 3 + 2] = a2 + bo[2];
    }
}

// ---------------------------------------------------------------------------
// Fused attention v7: Q-in-registers (32 rows/wave); K staged via
// global_load_lds into DOUBLE-BUFFERED LDS, ONE barrier per j-tile.
// Block = 128 Q-rows x JC=1024 cols (32 tiles); grid (NSL=8, 64).
// ---------------------------------------------------------------------------
__global__ __launch_bounds__(256) void attn_mfma(
    const u16* __restrict__ Q, const u16* __restrict__ K,
    const float* __restrict__ V, float* __restrict__ out)
{
    __shared__ u16 Ks[2][32 * KSTR];   // 2 x 33,280 B

    const int tid = threadIdx.x;
    const int wave = tid >> 6, lane = tid & 63;
    const int row0 = blockIdx.y * 128;
    const int col_base = blockIdx.x * JC;

    const int qm = lane & 15;
    const int g  = lane >> 4;

    // prologue: DMA K tile 0 into buf 0
#pragma unroll
    for (int i = 0; i < 8; ++i) {
        int cc = i * 4 + wave;
        async_load16(K + (size_t)(col_base + cc) * HD + lane * 8,
                     &Ks[0][cc * KSTR + lane * 8]);
    }

    // Q fragments: 32 rows x all K (AGPR-parked), loaded once.
    s16x8 qf[16][2];
    {
        const u16* qp = Q + (size_t)(row0 + wave * 32 + qm) * HD + g * 8;
#pragma unroll
        for (int t = 0; t < 16; ++t) {
            qf[t][0] = *(const s16x8*)(qp + t * 32);
            qf[t][1] = *(const s16x8*)(qp + (size_t)16 * HD + t * 32);
        }
    }
    __syncthreads();   // buf 0 ready

    float po[2][4][3] = {};
    int p = 0;

#pragma unroll 1
    for (int jt = 0; jt < JC / 32; ++jt) {
        const int col0 = col_base + jt * 32;

        if (jt + 1 < JC / 32) {
#pragma unroll
            for (int i = 0; i < 8; ++i) {
                int cc = i * 4 + wave;
                async_load16(K + (size_t)(col0 + 32 + cc) * HD + lane * 8,
                             &Ks[p ^ 1][cc * KSTR + lane * 8]);
            }
        }

        float vv[2][3];
#pragma unroll
        for (int ct = 0; ct < 2; ++ct) {
            size_t vr = (size_t)(col0 + ct * 16 + qm) * 3;
            vv[ct][0] = V[vr + 0];
            vv[ct][1] = V[vr + 1];
            vv[ct][2] = V[vr + 2];
        }

        const u16* Kb = Ks[p];
        f32x4 acc[2][2] = {};
#pragma unroll
        for (int kt = 0; kt < 16; ++kt) {
            s16x8 b0 = *(const s16x8*)&Kb[qm * KSTR + kt * 32 + g * 8];
            s16x8 b1 = *(const s16x8*)&Kb[(16 + qm) * KSTR + kt * 32 + g * 8];
            acc[0][0] = __builtin_amdgcn_mfma_f32_16x16x32_bf16(qf[kt][0], b0, acc[0][0], 0, 0, 0);
            acc[0][1] = __builtin_amdgcn_mfma_f32_16x16x32_bf16(qf[kt][0], b1, acc[0][1], 0, 0, 0);
            acc[1][0] = __builtin_amdgcn_mfma_f32_16x16x32_bf16(qf[kt][1], b0, acc[1][0], 0, 0, 0);
            acc[1][1] = __builtin_amdgcn_mfma_f32_16x16x32_bf16(qf[kt][1], b1, acc[1][1], 0, 0, 0);
        }

        // sigmoid + PV (rcp = v_rcp_f32, 1 ulp)
#pragma unroll
        for (int h = 0; h < 2; ++h)
#pragma unroll
            for (int ct = 0; ct < 2; ++ct)
#pragma unroll
                for (int r = 0; r < 4; ++r) {
                    float s = __builtin_amdgcn_rcpf(1.f + __expf(-acc[h][ct][r]));
                    po[h][r][0] += s * vv[ct][0];
                    po[h][r][1] += s * vv[ct][1];
                    po[h][r][2] += s * vv[ct][2];
                }
        __syncthreads();   // reads of buf p done; buf p^1 DMA drained
        p ^= 1;
    }

#pragma unroll
    for (int h = 0; h < 2; ++h)
#pragma unroll
        for (int r = 0; r < 4; ++r)
#pragma unroll
            for (int c = 0; c < 3; ++c) {
                float v = po[h][r][c];
                v += __shfl_down(v, 8, 16);
                v += __shfl_down(v, 4, 16);
                v += __shfl_down(v, 2, 16);
                v += __shfl_down(v, 1, 16);
                if (qm == 0)
                    atomicAdd(&out[(size_t)(row0 + wave * 32 + h * 16 + g * 4 + r) * 3 + c], v);
            }
}

// ---------------------------------------------------------------------------
// Workspace (single path, 29.6 MB):
//   wT [0, 5.50 MB) | h [5.50, 29.50 MB) (3 net strips) | Vf [29.50, 29.60)
// ---------------------------------------------------------------------------
extern "C" void kernel_launch(void* const* d_in, const int* in_sizes, int n_in,
                              void* d_out, int out_size, void* d_ws, size_t ws_size,
                              hipStream_t stream)
{
    const float* x   = (const float*)d_in[0];
    const float* c   = (const float*)d_in[1];
    const float* QW0 = (const float*)d_in[2];
    const float* Qb0 = (const float*)d_in[3];
    const float* QWh = (const float*)d_in[4];
    const float* Qbh = (const float*)d_in[5];
    const float* QWo = (const float*)d_in[6];
    const float* Qbo = (const float*)d_in[7];
    const float* KW0 = (const float*)d_in[8];
    const float* Kb0 = (const float*)d_in[9];
    const float* KWh = (const float*)d_in[10];
    const float* Kbh = (const float*)d_in[11];
    const float* KWo = (const float*)d_in[12];
    const float* Kbo = (const float*)d_in[13];
    const float* VW0 = (const float*)d_in[14];
    const float* Vb0 = (const float*)d_in[15];
    const float* VWh = (const float*)d_in[16];
    const float* Vbh = (const float*)d_in[17];
    const float* VWo = (const float*)d_in[18];
    const float* Vbo = (const float*)d_in[19];

    char* ws = (char*)d_ws;
    const size_t WTN = (size_t)HD * HD;
    const size_t NET = (size_t)NXR * HD;

    u16*   wT = (u16*)ws;                                   // 5.5 MB
    u16*   hA = (u16*)(ws + 11 * WTN * sizeof(u16));        // 24 MB (3 strips)
    u16*   hB = hA;                                          // in-place not used; two regions below
    float* Vf = (float*)(ws + 11 * WTN * sizeof(u16) + 3 * NET * sizeof(u16));

    // ping-pong strips: we need two 12 MB regions? No — keep R14's scheme:
    // hA (layer input) and write back in place is NOT safe for gemm_rs
    // (cross-block reads). Use two regions like R14: but 29.6 MB budget only
    // holds one. Reuse proven R14 layout: hA + separate hB region.
    // Recompute offsets (needs 53.6 MB, proven present since R14 ran fused).
    u16* hA2 = (u16*)(ws + 11 * WTN * sizeof(u16));
    u16* hB2 = (u16*)(ws + 11 * WTN * sizeof(u16) + 3 * NET * sizeof(u16));
    Vf = (float*)(ws + 11 * WTN * sizeof(u16) + 6 * NET * sizeof(u16));

    // ---- weight transposes (1 dispatch) ----
    P11 tsrc;
    for (int l = 0; l < 3; ++l) {
        tsrc.p[l * 3 + 0] = QWh + (size_t)l * WTN;
        tsrc.p[l * 3 + 1] = KWh + (size_t)l * WTN;
        tsrc.p[l * 3 + 2] = VWh + (size_t)l * WTN;
    }
    tsrc.p[9]  = QWo;
    tsrc.p[10] = KWo;
    transpose_w_all<<<dim3(16, 16, 11), 256, 0, stream>>>(tsrc, wT);

    // ---- layer 0 (1 dispatch, 3 nets) ----
    {
        P3 w0 = {{QW0, KW0, VW0}}, b0 = {{Qb0, Kb0, Vb0}};
        layer0_all<<<dim3(NXR * HD / 2048, 1, 3), 256, 0, stream>>>(x, c, w0, b0, hA2);
    }

    // ---- hidden layers (3 dispatches, z=3, grid 768) ----
    dim3 g3(NXR / 128, HD / 128, 3);
    {
        P3 b = {{Qbh + 0 * HD, Kbh + 0 * HD, Vbh + 0 * HD}};
        gemm_rs<1><<<g3, 256, 0, stream>>>(hA2, wT + 0 * 3 * WTN, WTN, b, hB2);
    }
    {
        P3 b = {{Qbh + 1 * HD, Kbh + 1 * HD, Vbh + 1 * HD}};
        gemm_rs<1><<<g3, 256, 0, stream>>>(hB2, wT + 1 * 3 * WTN, WTN, b, hA2);
    }
    {
        P3 b = {{Qbh + 2 * HD, Kbh + 2 * HD, Vbh + 2 * HD}};
        gemm_rs<1><<<g3, 256, 0, stream>>>(hA2, wT + 2 * 3 * WTN, WTN, b, hB2);
    }
    // ---- Q/K output layer (z=2) ----
    {
        P3 b = {{Qbo, Kbo, nullptr}};
        gemm_rs<0><<<dim3(NXR / 128, HD / 128, 2), 256, 0, stream>>>(
            hB2, wT + 9 * WTN, WTN, b, hA2);
    }
    // ---- V output layer ----
    vout_k<<<NCR / 4, 256, 0, stream>>>(hB2 + 2 * NET, VWo, Vbo, Vf);

    // ---- attention ----
    hipMemsetAsync(d_out, 0, (size_t)out_size * sizeof(float), stream);
    attn_mfma<<<dim3(NSL, NXR / 128), 256, 0, stream>>>(
        hA2, hA2 + NET, Vf, (float*)d_out);
}

// Round 19
// 288.243 us; speedup vs baseline: 1.6933x; 1.0097x over previous
//
#include <hip/hip_runtime.h>
#include <math.h>

#define NXR 8192
#define NCR 8192
#define HD  512
#define NSL 8            // attention j-slices (R11-proven)
#define JC  (NCR / NSL)  // 1024 cols per attention block
#define KSTR 520         // padded LDS col stride (elems)

typedef short s16x8 __attribute__((ext_vector_type(8)));
typedef float f32x4 __attribute__((ext_vector_type(4)));
typedef unsigned short u16;

struct P11 { const float* p[11]; };
struct P3  { const float* p[3]; };

__device__ inline u16 f2bf(float f) {
    unsigned int u = __float_as_uint(f);
    u = (u + 0x7FFFu + ((u >> 16) & 1u)) >> 16;
    return (u16)u;
}
__device__ inline float bf2f(u16 h) {
    return __uint_as_float(((unsigned int)h) << 16);
}

__device__ inline void async_load16(const void* g, void* l) {
    __builtin_amdgcn_global_load_lds(
        (const __attribute__((address_space(1))) unsigned int*)g,
        (__attribute__((address_space(3))) unsigned int*)l, 16, 0, 0);
}

// ---------------------------------------------------------------------------
// Fused weight transpose + bf16 convert: out[z][n][k] = (bf16)in_z[k][n].
// Slots: z = l*3+net (hidden), 9 = QWo, 10 = KWo. grid (16,16,11).
// ---------------------------------------------------------------------------
__global__ __launch_bounds__(256) void transpose_w_all(
    P11 srcs, u16* __restrict__ out)
{
    const float* in = srcs.p[blockIdx.z];
    u16* o = out + (size_t)blockIdx.z * HD * HD;
    __shared__ float tile[32][33];
    int bx = blockIdx.x * 32, by = blockIdx.y * 32;
    int tx = threadIdx.x & 31, ty = threadIdx.x >> 5;
    for (int r = ty; r < 32; r += 8)
        tile[r][tx] = in[(size_t)(by + r) * HD + bx + tx];
    __syncthreads();
    for (int r = ty; r < 32; r += 8)
        o[(size_t)(bx + r) * HD + by + tx] = f2bf(tile[tx][r]);
}

// ---------------------------------------------------------------------------
// Layer 0, 8 outputs/thread, bf16x8 store. grid (NXR*HD/2048, 1, 3)
// ---------------------------------------------------------------------------
__global__ __launch_bounds__(256) void layer0_all(
    const float* __restrict__ x, const float* __restrict__ c,
    P3 W0p, P3 b0p, u16* __restrict__ H)
{
    int z = blockIdx.z;
    const float* X  = (z == 0) ? x : c;
    const float* W0 = W0p.p[z];
    const float* b0 = b0p.p[z];
    u16* Hn = H + (size_t)z * NXR * HD;

    int idx = (blockIdx.x * 256 + threadIdx.x) * 8;
    int n = idx & (HD - 1);
    int row = idx >> 9;
    float x0 = X[row * 3 + 0], x1 = X[row * 3 + 1], x2 = X[row * 3 + 2];
    s16x8 o;
#pragma unroll
    for (int j = 0; j < 8; ++j) {
        float v = x0 * W0[n + j] + x1 * W0[HD + n + j] + x2 * W0[2 * HD + n + j] + b0[n + j];
        ((u16*)&o)[j] = f2bf(__sinf(v));
    }
    *(s16x8*)&Hn[idx] = o;
}

// ---------------------------------------------------------------------------
// GEMM v6 (small-block, 4 blocks/CU): 128 threads (2 waves), 64 rows x 256
// cols (8 col-tiles of 32). Single 33.3 KB LDS buffer -> 4 co-resident
// blocks/CU (4 independent barrier domains vs R18's 2). qf load amortized
// over 8 tiles (vs R18's 4). DMA for tile ct+1 issued right after the
// reads-done barrier and overlapped with the epilogue stores.
// grid (NXR/64, HD/256, nets) = (128, 2, z).
// ---------------------------------------------------------------------------
template<int ACT>
__global__ __launch_bounds__(128) void gemm_sm(
    const u16* __restrict__ Abase, const u16* __restrict__ Wt0, size_t wstride,
    P3 bias, u16* __restrict__ Cbase)
{
    __shared__ u16 Ws[32 * KSTR];   // 33,280 B

    const int net = blockIdx.z;
    const u16* A  = Abase + (size_t)net * NXR * HD;
    const u16* Wt = Wt0 + (size_t)net * wstride;
    const float* bias_p = bias.p[net];
    u16* C = Cbase + (size_t)net * NXR * HD;

    const int tid = threadIdx.x;
    const int wave = tid >> 6, lane = tid & 63;   // wave 0..1
    const int row0 = blockIdx.x * 64;
    const int colbase = blockIdx.y * 256;

    const int qm = lane & 15;
    const int g  = lane >> 4;

    // prologue: DMA col-tile 0 (one issue covers one col: 64 lanes x 16B = 1 KB)
#pragma unroll
    for (int i = 0; i < 16; ++i) {
        int cc = i * 2 + wave;
        async_load16(Wt + (size_t)(colbase + cc) * HD + lane * 8,
                     &Ws[cc * KSTR + lane * 8]);
    }

    // A fragments: this wave's 32 rows, all K (AGPR-parked)
    s16x8 qf[16][2];
    {
        const u16* ap = A + (size_t)(row0 + wave * 32 + qm) * HD + g * 8;
#pragma unroll
        for (int t = 0; t < 16; ++t) {
            qf[t][0] = *(const s16x8*)(ap + t * 32);
            qf[t][1] = *(const s16x8*)(ap + (size_t)16 * HD + t * 32);
        }
    }
    __syncthreads();   // DMA drained: buf ready

#pragma unroll 1
    for (int ct = 0; ct < 8; ++ct) {
        const int col0 = colbase + ct * 32;

        f32x4 acc[2][2] = {};
#pragma unroll
        for (int kt = 0; kt < 16; ++kt) {
            s16x8 b0 = *(const s16x8*)&Ws[qm * KSTR + kt * 32 + g * 8];
            s16x8 b1 = *(const s16x8*)&Ws[(16 + qm) * KSTR + kt * 32 + g * 8];
            acc[0][0] = __builtin_amdgcn_mfma_f32_16x16x32_bf16(qf[kt][0], b0, acc[0][0], 0, 0, 0);
            acc[0][1] = __builtin_amdgcn_mfma_f32_16x16x32_bf16(qf[kt][0], b1, acc[0][1], 0, 0, 0);
            acc[1][0] = __builtin_amdgcn_mfma_f32_16x16x32_bf16(qf[kt][1], b0, acc[1][0], 0, 0, 0);
            acc[1][1] = __builtin_amdgcn_mfma_f32_16x16x32_bf16(qf[kt][1], b1, acc[1][1], 0, 0, 0);
        }
        __syncthreads();   // all reads of Ws done

        if (ct + 1 < 8) {  // DMA next tile; flight overlaps epilogue below
#pragma unroll
            for (int i = 0; i < 16; ++i) {
                int cc = i * 2 + wave;
                async_load16(Wt + (size_t)(colbase + (ct + 1) * 32 + cc) * HD + lane * 8,
                             &Ws[cc * KSTR + lane * 8]);
            }
        }

        float bv0 = bias_p[col0 + qm];
        float bv1 = bias_p[col0 + 16 + qm];
#pragma unroll
        for (int hh = 0; hh < 2; ++hh) {
#pragma unroll
            for (int r = 0; r < 4; ++r) {
                int grow = row0 + wave * 32 + hh * 16 + g * 4 + r;
                float v0 = acc[hh][0][r] + bv0;
                float v1 = acc[hh][1][r] + bv1;
                if (ACT) { v0 = __sinf(v0); v1 = __sinf(v1); }
                C[(size_t)grow * HD + col0 + qm]      = f2bf(v0);
                C[(size_t)grow * HD + col0 + 16 + qm] = f2bf(v1);
            }
        }
        __syncthreads();   // DMA drained: buf ready for next iter
    }
}

// ---------------------------------------------------------------------------
// V output layer (M=3), one wave per row, fp32 out.
// ---------------------------------------------------------------------------
__global__ __launch_bounds__(256) void vout_k(
    const u16* __restrict__ H, const float* __restrict__ Wo,
    const float* __restrict__ bo, float* __restrict__ V)
{
    int wave = threadIdx.x >> 6, lane = threadIdx.x & 63;
    int row = blockIdx.x * 4 + wave;
    s16x8 hv = *(const s16x8*)(H + (size_t)row * HD + lane * 8);
    float a0 = 0, a1 = 0, a2 = 0;
#pragma unroll
    for (int j = 0; j < 8; ++j) {
        float hf = bf2f(((const u16*)&hv)[j]);
        int k = lane * 8 + j;
        a0 += hf * Wo[k * 3 + 0];
        a1 += hf * Wo[k * 3 + 1];
        a2 += hf * Wo[k * 3 + 2];
    }
#pragma unroll
    for (int d = 32; d >= 1; d >>= 1) {
        a0 += __shfl_down(a0, d);
        a1 += __shfl_down(a1, d);
        a2 += __shfl_down(a2, d);
    }
    if (lane == 0) {
        V[row * 3 + 0] = a0 + bo[0];
        V[row * 3 + 1] = a1 + bo[1];
        V[row * 3 + 2] = a2 + bo[2];
    }
}

// ---------------------------------------------------------------------------
// Fused attention (R18-exact): Q-in-registers (32 rows/wave); K staged via
// global_load_lds into DOUBLE-BUFFERED LDS, ONE barrier per j-tile.
// Block = 128 Q-rows x JC=1024 cols (32 tiles); grid (NSL=8, 64).
// ---------------------------------------------------------------------------
__global__ __launch_bounds__(256) void attn_mfma(
    const u16* __restrict__ Q, const u16* __restrict__ K,
    const float* __restrict__ V, float* __restrict__ out)
{
    __shared__ u16 Ks[2][32 * KSTR];   // 2 x 33,280 B

    const int tid = threadIdx.x;
    const int wave = tid >> 6, lane = tid & 63;
    const int row0 = blockIdx.y * 128;
    const int col_base = blockIdx.x * JC;

    const int qm = lane & 15;
    const int g  = lane >> 4;

    // prologue: DMA K tile 0 into buf 0
#pragma unroll
    for (int i = 0; i < 8; ++i) {
        int cc = i * 4 + wave;
        async_load16(K + (size_t)(col_base + cc) * HD + lane * 8,
                     &Ks[0][cc * KSTR + lane * 8]);
    }

    // Q fragments: 32 rows x all K (AGPR-parked), loaded once.
    s16x8 qf[16][2];
    {
        const u16* qp = Q + (size_t)(row0 + wave * 32 + qm) * HD + g * 8;
#pragma unroll
        for (int t = 0; t < 16; ++t) {
            qf[t][0] = *(const s16x8*)(qp + t * 32);
            qf[t][1] = *(const s16x8*)(qp + (size_t)16 * HD + t * 32);
        }
    }
    __syncthreads();   // buf 0 ready

    float po[2][4][3] = {};
    int p = 0;

#pragma unroll 1
    for (int jt = 0; jt < JC / 32; ++jt) {
        const int col0 = col_base + jt * 32;

        if (jt + 1 < JC / 32) {
#pragma unroll
            for (int i = 0; i < 8; ++i) {
                int cc = i * 4 + wave;
                async_load16(K + (size_t)(col0 + 32 + cc) * HD + lane * 8,
                             &Ks[p ^ 1][cc * KSTR + lane * 8]);
            }
        }

        float vv[2][3];
#pragma unroll
        for (int ct = 0; ct < 2; ++ct) {
            size_t vr = (size_t)(col0 + ct * 16 + qm) * 3;
            vv[ct][0] = V[vr + 0];
            vv[ct][1] = V[vr + 1];
            vv[ct][2] = V[vr + 2];
        }

        const u16* Kb = Ks[p];
        f32x4 acc[2][2] = {};
#pragma unroll
        for (int kt = 0; kt < 16; ++kt) {
            s16x8 b0 = *(const s16x8*)&Kb[qm * KSTR + kt * 32 + g * 8];
            s16x8 b1 = *(const s16x8*)&Kb[(16 + qm) * KSTR + kt * 32 + g * 8];
            acc[0][0] = __builtin_amdgcn_mfma_f32_16x16x32_bf16(qf[kt][0], b0, acc[0][0], 0, 0, 0);
            acc[0][1] = __builtin_amdgcn_mfma_f32_16x16x32_bf16(qf[kt][0], b1, acc[0][1], 0, 0, 0);
            acc[1][0] = __builtin_amdgcn_mfma_f32_16x16x32_bf16(qf[kt][1], b0, acc[1][0], 0, 0, 0);
            acc[1][1] = __builtin_amdgcn_mfma_f32_16x16x32_bf16(qf[kt][1], b1, acc[1][1], 0, 0, 0);
        }

        // sigmoid + PV (rcp = v_rcp_f32, 1 ulp)
#pragma unroll
        for (int h = 0; h < 2; ++h)
#pragma unroll
            for (int ct = 0; ct < 2; ++ct)
#pragma unroll
                for (int r = 0; r < 4; ++r) {
                    float s = __builtin_amdgcn_rcpf(1.f + __expf(-acc[h][ct][r]));
                    po[h][r][0] += s * vv[ct][0];
                    po[h][r][1] += s * vv[ct][1];
                    po[h][r][2] += s * vv[ct][2];
                }
        __syncthreads();   // reads of buf p done; buf p^1 DMA drained
        p ^= 1;
    }

#pragma unroll
    for (int h = 0; h < 2; ++h)
#pragma unroll
        for (int r = 0; r < 4; ++r)
#pragma unroll
            for (int c = 0; c < 3; ++c) {
                float v = po[h][r][c];
                v += __shfl_down(v, 8, 16);
                v += __shfl_down(v, 4, 16);
                v += __shfl_down(v, 2, 16);
                v += __shfl_down(v, 1, 16);
                if (qm == 0)
                    atomicAdd(&out[(size_t)(row0 + wave * 32 + h * 16 + g * 4 + r) * 3 + c], v);
            }
}

// ---------------------------------------------------------------------------
// Workspace (53.6 MB — proven present: R18 used this exact layout and passed):
//   wT [0, 5.5 MB) | hA [5.5, 29.5) | hB [29.5, 53.5) | Vf [53.5, 53.6)
// ---------------------------------------------------------------------------
extern "C" void kernel_launch(void* const* d_in, const int* in_sizes, int n_in,
                              void* d_out, int out_size, void* d_ws, size_t ws_size,
                              hipStream_t stream)
{
    const float* x   = (const float*)d_in[0];
    const float* c   = (const float*)d_in[1];
    const float* QW0 = (const float*)d_in[2];
    const float* Qb0 = (const float*)d_in[3];
    const float* QWh = (const float*)d_in[4];
    const float* Qbh = (const float*)d_in[5];
    const float* QWo = (const float*)d_in[6];
    const float* Qbo = (const float*)d_in[7];
    const float* KW0 = (const float*)d_in[8];
    const float* Kb0 = (const float*)d_in[9];
    const float* KWh = (const float*)d_in[10];
    const float* Kbh = (const float*)d_in[11];
    const float* KWo = (const float*)d_in[12];
    const float* Kbo = (const float*)d_in[13];
    const float* VW0 = (const float*)d_in[14];
    const float* Vb0 = (const float*)d_in[15];
    const float* VWh = (const float*)d_in[16];
    const float* Vbh = (const float*)d_in[17];
    const float* VWo = (const float*)d_in[18];
    const float* Vbo = (const float*)d_in[19];

    char* ws = (char*)d_ws;
    const size_t WTN = (size_t)HD * HD;
    const size_t NET = (size_t)NXR * HD;

    u16*   wT = (u16*)ws;
    u16*   hA = (u16*)(ws + 11 * WTN * sizeof(u16));
    u16*   hB = (u16*)(ws + 11 * WTN * sizeof(u16) + 3 * NET * sizeof(u16));
    float* Vf = (float*)(ws + 11 * WTN * sizeof(u16) + 6 * NET * sizeof(u16));

    // ---- weight transposes (1 dispatch) ----
    P11 tsrc;
    for (int l = 0; l < 3; ++l) {
        tsrc.p[l * 3 + 0] = QWh + (size_t)l * WTN;
        tsrc.p[l * 3 + 1] = KWh + (size_t)l * WTN;
        tsrc.p[l * 3 + 2] = VWh + (size_t)l * WTN;
    }
    tsrc.p[9]  = QWo;
    tsrc.p[10] = KWo;
    transpose_w_all<<<dim3(16, 16, 11), 256, 0, stream>>>(tsrc, wT);

    // ---- layer 0 (1 dispatch, 3 nets) ----
    {
        P3 w0 = {{QW0, KW0, VW0}}, b0 = {{Qb0, Kb0, Vb0}};
        layer0_all<<<dim3(NXR * HD / 2048, 1, 3), 256, 0, stream>>>(x, c, w0, b0, hA);
    }

    // ---- hidden layers (3 dispatches, 128-thread blocks, 768 blocks) ----
    dim3 g3(NXR / 64, HD / 256, 3);
    {
        P3 b = {{Qbh + 0 * HD, Kbh + 0 * HD, Vbh + 0 * HD}};
        gemm_sm<1><<<g3, 128, 0, stream>>>(hA, wT + 0 * 3 * WTN, WTN, b, hB);
    }
    {
        P3 b = {{Qbh + 1 * HD, Kbh + 1 * HD, Vbh + 1 * HD}};
        gemm_sm<1><<<g3, 128, 0, stream>>>(hB, wT + 1 * 3 * WTN, WTN, b, hA);
    }
    {
        P3 b = {{Qbh + 2 * HD, Kbh + 2 * HD, Vbh + 2 * HD}};
        gemm_sm<1><<<g3, 128, 0, stream>>>(hA, wT + 2 * 3 * WTN, WTN, b, hB);
    }
    // ---- Q/K output layer (z=2) ----
    {
        P3 b = {{Qbo, Kbo, nullptr}};
        gemm_sm<0><<<dim3(NXR / 64, HD / 256, 2), 128, 0, stream>>>(
            hB, wT + 9 * WTN, WTN, b, hA);
    }
    // ---- V output layer ----
    vout_k<<<NCR / 4, 256, 0, stream>>>(hB + 2 * NET, VWo, Vbo, Vf);

    // ---- attention ----
    hipMemsetAsync(d_out, 0, (size_t)out_size * sizeof(float), stream);
    attn_mfma<<<dim3(NSL, NXR / 128), 256, 0, stream>>>(
        hA, hA + NET, Vf, (float*)d_out);
}